// Round 10
// baseline (246.708 us; speedup 1.0000x reference)
//
#include <hip/hip_runtime.h>

#define NN 8192     // nodes
#define NB 32       // graphs
#define NG 256      // nodes per graph
#define NE 65536    // edges per graph type
#define DK 512
#define HC 32
#define DB 2048     // body visual dim
#define DF 512      // face visual dim

#define BODY_DW (NN*DB/4)            // 4194304 dwords of fp8x4 (body)
#define FACE_DW (NN*DF/4)            // 1048576 dwords of fp8x4 (face)
#define PB_BODY (BODY_DW/2048)       // 2048 pack blocks (body), 2048 dw/block
#define PB_FACE (FACE_DW/2048)       // 512 pack blocks (face)

typedef float v2f __attribute__((ext_vector_type(2)));

#if __has_builtin(__builtin_amdgcn_cvt_pk_f32_fp8) && __has_builtin(__builtin_amdgcn_cvt_pk_fp8_f32)
#define HW_FP8 1
#else
#define HW_FP8 0
#endif

// ---- fp8 e4m3fn helpers (manual fallback only if builtins missing) ----
__device__ __forceinline__ float fp8_dec(unsigned u) {
    unsigned e = (u >> 3) & 15u, m = u & 7u, s = u & 0x80u;
    float v = e ? __uint_as_float(((e + 120u) << 23) | (m << 20))
                : (float)m * 0.001953125f;
    return s ? -v : v;
}
__device__ __forceinline__ unsigned fp8_enc(float x) {
    unsigned sb = (__float_as_uint(x) >> 24) & 0x80u;
    float a = fabsf(x);
    if (a >= 448.f) return sb | 0x7Eu;
    if (a < 0.015625f) {
        int c = (int)rintf(a * 512.f);
        if (c > 7) return sb | 0x08u;
        return sb | (unsigned)c;
    }
    int ex; (void)frexpf(a, &ex);
    float p = ldexpf(a, 1 - ex);
    int m = (int)rintf((p - 1.f) * 8.f);
    int e = ex - 1 + 7;
    if (m == 8) { m = 0; e++; }
    if (e >= 16) return sb | 0x7Eu;
    return sb | (unsigned)(e << 3) | (unsigned)m;
}
__device__ __forceinline__ unsigned pack4_fp8(float4 v) {
#if HW_FP8
    int u = __builtin_amdgcn_cvt_pk_fp8_f32(v.x, v.y, 0, false);
    u = __builtin_amdgcn_cvt_pk_fp8_f32(v.z, v.w, u, true);
    return (unsigned)u;
#else
    return fp8_enc(v.x) | (fp8_enc(v.y) << 8) | (fp8_enc(v.z) << 16) | (fp8_enc(v.w) << 24);
#endif
}
__device__ __forceinline__ float fp8dot4(unsigned a, unsigned b) {
#if HW_FP8
    v2f al = __builtin_amdgcn_cvt_pk_f32_fp8((int)a, false);
    v2f ah = __builtin_amdgcn_cvt_pk_f32_fp8((int)a, true);
    v2f bl = __builtin_amdgcn_cvt_pk_f32_fp8((int)b, false);
    v2f bh = __builtin_amdgcn_cvt_pk_f32_fp8((int)b, true);
    return al.x*bl.x + al.y*bl.y + ah.x*bh.x + ah.y*bh.y;
#else
    float s = 0.f;
    #pragma unroll
    for (int j = 0; j < 4; j++)
        s += fp8_dec((a >> (8*j)) & 255u) * fp8_dec((b >> (8*j)) & 255u);
    return s;
#endif
}
__device__ __forceinline__ float fp8dot16(int4 a, int4 b) {
    return fp8dot4((unsigned)a.x, (unsigned)b.x) + fp8dot4((unsigned)a.y, (unsigned)b.y)
         + fp8dot4((unsigned)a.z, (unsigned)b.z) + fp8dot4((unsigned)a.w, (unsigned)b.w);
}

struct Params {
    const float *vb, *vf, *x, *Wq, *Wk, *Wv, *ln_g, *ln_b, *prelu_a;
    const float *mlp_W, *mlp_b, *np_W, *np_b, *body_W, *body_b, *face_W, *face_b;
    const float *pb_W, *pb_b, *pf_W, *pf_b;
    const int *eib, *eif;
    unsigned *vnb, *vnf;
    float *invb, *invf;
    float *a_ws, *ns, *hlb, *hlf, *w;
    int *counts, *starts, *cursor, *esrc, *edst;
    float *out;
};

// ===== K0: degree count + rank-2 attention (small) =====
// blocks [0, 512)   : degree count
// blocks [512, +NB) : attention
__global__ __launch_bounds__(256) void k0_kernel(Params p) {
    __shared__ float2 xs[NG];
    __shared__ float pm[4][4];
    __shared__ float sm4[4];
    const int bid = blockIdx.x, tid = threadIdx.x;
    const int lane = tid & 63, wave = tid >> 6;
    if (bid < 512) {
        const int e = bid * 256 + tid;
        if (e < NE) atomicAdd(&p.counts[p.eib[NE + e]], 1);
        else        atomicAdd(&p.counts[NN + p.eif[NE + (e - NE)]], 1);
    } else {
        const int gg = bid - 512;
        xs[tid] = ((const float2*)p.x)[gg*NG + tid];
        const int d = tid * 2;
        float q0a = p.Wq[d],    q0b = p.Wq[d+1];
        float q1a = p.Wq[DK+d], q1b = p.Wq[DK+d+1];
        float k0a = p.Wk[d],    k0b = p.Wk[d+1];
        float k1a = p.Wk[DK+d], k1b = p.Wk[DK+d+1];
        float m00 = q0a*k0a + q0b*k0b;
        float m01 = q0a*k1a + q0b*k1b;
        float m10 = q1a*k0a + q1b*k0b;
        float m11 = q1a*k1a + q1b*k1b;
        #pragma unroll
        for (int off = 32; off > 0; off >>= 1) {
            m00 += __shfl_down(m00,off); m01 += __shfl_down(m01,off);
            m10 += __shfl_down(m10,off); m11 += __shfl_down(m11,off);
        }
        if (lane == 0) { pm[wave][0]=m00; pm[wave][1]=m01; pm[wave][2]=m10; pm[wave][3]=m11; }
        __syncthreads();
        if (tid < 4) sm4[tid] = pm[0][tid] + pm[1][tid] + pm[2][tid] + pm[3][tid];
        __syncthreads();
        const float scale = 0.04419417382415922f;  // 1/sqrt(512)
        const float2 xi = xs[tid];
        const float u0 = (xi.x*sm4[0] + xi.y*sm4[2]) * scale;
        const float u1 = (xi.x*sm4[1] + xi.y*sm4[3]) * scale;
        float m = -1e30f;
        for (int j = 0; j < NG; j++) m = fmaxf(m, u0*xs[j].x + u1*xs[j].y);
        float S = 0.f, a0 = 0.f, a1 = 0.f;
        for (int j = 0; j < NG; j++) {
            float2 xj = xs[j];
            float pr = __expf(u0*xj.x + u1*xj.y - m);
            S += pr; a0 += pr*xj.x; a1 += pr*xj.y;
        }
        const float invS = 1.f / S;
        ((float2*)p.a_ws)[gg*NG + tid] = make_float2(a0*invS, a1*invS);
    }
}

// ===== K1: pure streaming fp8 pack — branch-free, 8 loads hoisted =====
// blocks [0, PB_BODY)           : body (2048 dwords each)
// blocks [PB_BODY, +PB_FACE)    : face
__global__ __launch_bounds__(256) void k1_kernel(Params p) {
    const int bid = blockIdx.x, tid = threadIdx.x;
    const float4* src;
    unsigned* dst;
    size_t base;
    if (bid < PB_BODY) { src = (const float4*)p.vb; dst = p.vnb; base = (size_t)bid * 2048; }
    else               { src = (const float4*)p.vf; dst = p.vnf; base = (size_t)(bid - PB_BODY) * 2048; }
    const float4* s = src + base + tid;
    unsigned* o = dst + base + tid;
    float4 v0 = s[0],    v1 = s[256],  v2 = s[512],  v3 = s[768];
    float4 v4 = s[1024], v5 = s[1280], v6 = s[1536], v7 = s[1792];
    o[0]    = pack4_fp8(v0);
    o[256]  = pack4_fp8(v1);
    o[512]  = pack4_fp8(v2);
    o[768]  = pack4_fp8(v3);
    o[1024] = pack4_fp8(v4);
    o[1280] = pack4_fp8(v5);
    o[1536] = pack4_fp8(v6);
    o[1792] = pack4_fp8(v7);
}

// ===== K2: CSR scan + node MLP pipeline + invnorm from fp8 tables =====
// blocks 0,1                         : exclusive scan
// blocks [2, 2+NN/4)                 : node pipeline (1 node / wave)
// blocks [2+NN/4, 2+NN/2)            : body invnorm (1 row / wave)
// blocks [2+NN/2, 2+3NN/4)           : face invnorm (1 row / wave)
__global__ __launch_bounds__(256) void k2_kernel(Params p) {
    __shared__ int part[256];
    __shared__ float t[4][DK];
    __shared__ float hbuf[4][HC];
    const int bid = blockIdx.x, tid = threadIdx.x;
    const int wave = tid >> 6, lane = tid & 63;
    const int B_NODE = NN/4;

    if (bid < 2) {
        const int cbase = bid * NN;
        const int sbase = bid * (NN + 1);
        int loc[32];
        int sum = 0;
        #pragma unroll
        for (int j = 0; j < 32; j++) { loc[j] = p.counts[cbase + tid*32 + j]; sum += loc[j]; }
        part[tid] = sum;
        __syncthreads();
        for (int off = 1; off < 256; off <<= 1) {
            int v = (tid >= off) ? part[tid - off] : 0;
            __syncthreads();
            part[tid] += v;
            __syncthreads();
        }
        int run = (tid == 0) ? 0 : part[tid - 1];
        #pragma unroll
        for (int j = 0; j < 32; j++) {
            p.starts[sbase + tid*32 + j] = run;
            p.cursor[cbase + tid*32 + j] = run;
            run += loc[j];
        }
        if (tid == 255) p.starts[sbase + NN] = run;
        return;
    }
    if (bid < 2 + B_NODE) {
        const int node = (bid - 2) * 4 + wave;
        const float a0 = p.a_ws[node*2], a1 = p.a_ws[node*2+1];
        const float4* wv0 = (const float4*)p.Wv;
        const float4* wv1 = (const float4*)(p.Wv + DK);
        const float4* g4 = (const float4*)p.ln_g;
        const float4* b4 = (const float4*)p.ln_b;
        float4 W0[2], W1[2], Gg[2], Bb[2];
        #pragma unroll
        for (int k = 0; k < 2; k++) {
            int c4 = lane*2 + k;
            W0[k] = wv0[c4]; W1[k] = wv1[c4]; Gg[k] = g4[c4]; Bb[k] = b4[c4];
        }
        float s0=0.f, s1=0.f, q00=0.f, q01=0.f, q11=0.f;
        #pragma unroll
        for (int k = 0; k < 2; k++) {
            const float* u = (const float*)&W0[k];
            const float* v = (const float*)&W1[k];
            #pragma unroll
            for (int j = 0; j < 4; j++) {
                s0 += u[j]; s1 += v[j];
                q00 += u[j]*u[j]; q01 += u[j]*v[j]; q11 += v[j]*v[j];
            }
        }
        #pragma unroll
        for (int off = 1; off < 64; off <<= 1) {
            s0 += __shfl_xor(s0,off); s1 += __shfl_xor(s1,off);
            q00 += __shfl_xor(q00,off); q01 += __shfl_xor(q01,off); q11 += __shfl_xor(q11,off);
        }
        const float mean = (a0*s0 + a1*s1) * (1.f/DK);
        const float msq  = (a0*a0*q00 + 2.f*a0*a1*q01 + a1*a1*q11) * (1.f/DK);
        const float inv  = rsqrtf(msq - mean*mean + 1e-5f);
        const float alpha = p.prelu_a[0];
        #pragma unroll
        for (int k = 0; k < 2; k++) {
            int c4 = lane*2 + k;
            const float* u = (const float*)&W0[k];
            const float* v = (const float*)&W1[k];
            const float* gf = (const float*)&Gg[k];
            const float* bf = (const float*)&Bb[k];
            #pragma unroll
            for (int j = 0; j < 4; j++) {
                float od = a0*u[j] + a1*v[j];
                float nd = (od - mean) * inv * gf[j] + bf[j];
                t[wave][c4*4 + j] = (nd >= 0.f) ? nd : alpha*nd;
            }
        }
        __syncthreads();
        const int c = lane & 31, half = lane >> 5;
        const float* tp = t[wave] + half*256;
        const float* mw = p.mlp_W + half*256*HC + c;
        float partl = 0.f;
        for (int d = 0; d < 256; d++) partl += tp[d] * mw[d*HC];
        partl += __shfl_down(partl, 32);
        float hc = 0.f;
        if (lane < 32) { hc = partl + p.mlp_b[c]; hbuf[wave][c] = hc; }
        __syncthreads();
        float sp = (lane < 32) ? hc * p.np_W[c] : 0.f;
        #pragma unroll
        for (int off = 16; off > 0; off >>= 1) sp += __shfl_down(sp, off);
        if (lane == 0) p.ns[node] = sp + p.np_b[0];
        const float* hb_ = hbuf[wave];
        if (lane < 32) {
            float acc2 = p.body_b[c];
            #pragma unroll 8
            for (int cp = 0; cp < HC; cp++) acc2 += hb_[cp] * p.body_W[cp*HC + c];
            p.hlb[(size_t)node*HC + c] = acc2;
        } else {
            float acc2 = p.face_b[c];
            #pragma unroll 8
            for (int cp = 0; cp < HC; cp++) acc2 += hb_[cp] * p.face_W[cp*HC + c];
            p.hlf[(size_t)node*HC + c] = acc2;
        }
        return;
    }
    if (bid < 2 + B_NODE + NN/4) {
        const int node = (bid - 2 - B_NODE) * 4 + wave;
        const unsigned* row = p.vnb + (size_t)node * (DB/4);
        float ss = 0.f;
        #pragma unroll
        for (int k = 0; k < 8; k++) {
            unsigned u = row[lane + 64*k];
            ss += fp8dot4(u, u);
        }
        #pragma unroll
        for (int off = 1; off < 64; off <<= 1) ss += __shfl_xor(ss, off);
        if (lane == 0) p.invb[node] = rsqrtf(ss + 1e-8f);
        return;
    }
    {
        const int node = (bid - 2 - B_NODE - NN/4) * 4 + wave;
        const unsigned* row = p.vnf + (size_t)node * (DF/4);
        unsigned u0 = row[lane], u1 = row[lane + 64];
        float ss = fp8dot4(u0, u0) + fp8dot4(u1, u1);
        #pragma unroll
        for (int off = 1; off < 64; off <<= 1) ss += __shfl_xor(ss, off);
        if (lane == 0) p.invf[node] = rsqrtf(ss + 1e-8f);
    }
}

// ===== K3: CSR fill =====
__global__ __launch_bounds__(256) void fill_kernel(Params p) {
    const int e = blockIdx.x * 256 + threadIdx.x;
    if (e < NE) {
        int s = p.eib[e], d = p.eib[NE + e];
        int pos = atomicAdd(&p.cursor[d], 1);
        p.esrc[pos] = s; p.edst[pos] = d;
    } else {
        int e2 = e - NE;
        int s = p.eif[e2], d = p.eif[NE + e2];
        int pos = atomicAdd(&p.cursor[NN + d], 1);
        p.esrc[NE + pos] = s; p.edst[NE + pos] = d;
    }
}

// ===== K4: edge cosines in CSR order (4 edges / wave) =====
__global__ __launch_bounds__(256) void wdot_kernel(Params p) {
    const int wave = threadIdx.x >> 6, lane = threadIdx.x & 63;
    const int BB = NE/16;
    float d0, d1, d2, d3;
    int i0;
    int s0, s1, s2, s3, t0, t1, t2, t3;
    const float* invp;
    if (blockIdx.x < BB) {
        i0 = (blockIdx.x * 4 + wave) * 4;
        invp = p.invb;
        s0 = p.esrc[i0];   t0 = p.edst[i0];
        s1 = p.esrc[i0+1]; t1 = p.edst[i0+1];
        s2 = p.esrc[i0+2]; t2 = p.edst[i0+2];
        s3 = p.esrc[i0+3]; t3 = p.edst[i0+3];
        const int4* A0 = (const int4*)(p.vnb + (size_t)s0 * (DB/4));
        const int4* B0 = (const int4*)(p.vnb + (size_t)t0 * (DB/4));
        const int4* A1 = (const int4*)(p.vnb + (size_t)s1 * (DB/4));
        const int4* B1 = (const int4*)(p.vnb + (size_t)t1 * (DB/4));
        const int4* A2 = (const int4*)(p.vnb + (size_t)s2 * (DB/4));
        const int4* B2 = (const int4*)(p.vnb + (size_t)t2 * (DB/4));
        const int4* A3 = (const int4*)(p.vnb + (size_t)s3 * (DB/4));
        const int4* B3 = (const int4*)(p.vnb + (size_t)t3 * (DB/4));
        int4 a00 = A0[lane], a01 = A0[lane+64];
        int4 b00 = B0[lane], b01 = B0[lane+64];
        int4 a10 = A1[lane], a11 = A1[lane+64];
        int4 b10 = B1[lane], b11 = B1[lane+64];
        int4 a20 = A2[lane], a21 = A2[lane+64];
        int4 b20 = B2[lane], b21 = B2[lane+64];
        int4 a30 = A3[lane], a31 = A3[lane+64];
        int4 b30 = B3[lane], b31 = B3[lane+64];
        d0 = fp8dot16(a00,b00) + fp8dot16(a01,b01);
        d1 = fp8dot16(a10,b10) + fp8dot16(a11,b11);
        d2 = fp8dot16(a20,b20) + fp8dot16(a21,b21);
        d3 = fp8dot16(a30,b30) + fp8dot16(a31,b31);
    } else {
        i0 = NE + ((blockIdx.x - BB) * 4 + wave) * 4;
        invp = p.invf;
        s0 = p.esrc[i0];   t0 = p.edst[i0];
        s1 = p.esrc[i0+1]; t1 = p.edst[i0+1];
        s2 = p.esrc[i0+2]; t2 = p.edst[i0+2];
        s3 = p.esrc[i0+3]; t3 = p.edst[i0+3];
        const int2* A0 = (const int2*)(p.vnf + (size_t)s0 * (DF/4));
        const int2* B0 = (const int2*)(p.vnf + (size_t)t0 * (DF/4));
        const int2* A1 = (const int2*)(p.vnf + (size_t)s1 * (DF/4));
        const int2* B1 = (const int2*)(p.vnf + (size_t)t1 * (DF/4));
        const int2* A2 = (const int2*)(p.vnf + (size_t)s2 * (DF/4));
        const int2* B2 = (const int2*)(p.vnf + (size_t)t2 * (DF/4));
        const int2* A3 = (const int2*)(p.vnf + (size_t)s3 * (DF/4));
        const int2* B3 = (const int2*)(p.vnf + (size_t)t3 * (DF/4));
        int2 a0 = A0[lane], b0 = B0[lane];
        int2 a1 = A1[lane], b1 = B1[lane];
        int2 a2 = A2[lane], b2 = B2[lane];
        int2 a3 = A3[lane], b3 = B3[lane];
        d0 = fp8dot4((unsigned)a0.x,(unsigned)b0.x) + fp8dot4((unsigned)a0.y,(unsigned)b0.y);
        d1 = fp8dot4((unsigned)a1.x,(unsigned)b1.x) + fp8dot4((unsigned)a1.y,(unsigned)b1.y);
        d2 = fp8dot4((unsigned)a2.x,(unsigned)b2.x) + fp8dot4((unsigned)a2.y,(unsigned)b2.y);
        d3 = fp8dot4((unsigned)a3.x,(unsigned)b3.x) + fp8dot4((unsigned)a3.y,(unsigned)b3.y);
    }
    #pragma unroll
    for (int off = 1; off < 64; off <<= 1) {
        d0 += __shfl_xor(d0, off);
        d1 += __shfl_xor(d1, off);
        d2 += __shfl_xor(d2, off);
        d3 += __shfl_xor(d3, off);
    }
    if (lane == 0) {
        d0 *= invp[s0] * invp[t0];
        d1 *= invp[s1] * invp[t1];
        d2 *= invp[s2] * invp[t2];
        d3 *= invp[s3] * invp[t3];
        ((float4*)p.w)[i0 >> 2] = make_float4(d0, d1, d2, d3);
    }
}

// ===== K5: CSR gather + projections + final =====
__global__ __launch_bounds__(256) void gather_kernel(Params p) {
    const int wave = threadIdx.x >> 6, lane = threadIdx.x & 63;
    const int node = blockIdx.x * 4 + wave;
    const bool bodyhalf = lane < 32;
    const int c = lane & 31;
    const int sbase = bodyhalf ? 0 : (NN + 1);
    const int eofs = bodyhalf ? 0 : NE;
    const float* hl = bodyhalf ? p.hlb : p.hlf;
    const int s0 = p.starts[sbase + node], s1 = p.starts[sbase + node + 1];
    float acc = 0.f;
    for (int i = s0; i < s1; i++) {
        float wv = p.w[eofs + i];
        int s = p.esrc[eofs + i];
        acc += wv * hl[(size_t)s * HC + c];
    }
    float pr = acc * (bodyhalf ? p.pb_W : p.pf_W)[c];
    #pragma unroll
    for (int off = 16; off > 0; off >>= 1) pr += __shfl_down(pr, off);
    float tot = __shfl(pr, 0) + __shfl(pr, 32);
    if (lane == 0) p.out[node] = p.ns[node] + tot + p.pb_b[0] + p.pf_b[0];
}

extern "C" void kernel_launch(void* const* d_in, const int* in_sizes, int n_in,
                              void* d_out, int out_size, void* d_ws, size_t ws_size,
                              hipStream_t stream) {
    char* ws = (char*)d_ws;
    size_t off = 0;
    auto alloc = [&](size_t bytes) { void* pp = ws + off; off += (bytes + 15) & ~size_t(15); return pp; };

    Params p;
    p.vb      = (const float*)d_in[1];
    p.vf      = (const float*)d_in[2];
    p.x       = (const float*)d_in[0];
    p.Wq      = (const float*)d_in[3];
    p.Wk      = (const float*)d_in[4];
    p.Wv      = (const float*)d_in[5];
    p.ln_g    = (const float*)d_in[6];
    p.ln_b    = (const float*)d_in[7];
    p.prelu_a = (const float*)d_in[8];
    p.mlp_W   = (const float*)d_in[9];
    p.mlp_b   = (const float*)d_in[10];
    p.np_W    = (const float*)d_in[11];
    p.np_b    = (const float*)d_in[12];
    p.body_W  = (const float*)d_in[13];
    p.body_b  = (const float*)d_in[14];
    p.face_W  = (const float*)d_in[15];
    p.face_b  = (const float*)d_in[16];
    p.pb_W    = (const float*)d_in[17];
    p.pb_b    = (const float*)d_in[18];
    p.pf_W    = (const float*)d_in[19];
    p.pf_b    = (const float*)d_in[20];
    p.eib     = (const int*)d_in[21];
    p.eif     = (const int*)d_in[22];
    p.vnb     = (unsigned*)alloc((size_t)BODY_DW*4);     // 16 MB fp8
    p.vnf     = (unsigned*)alloc((size_t)FACE_DW*4);     //  4 MB fp8
    p.invb    = (float*)alloc((size_t)NN*4);
    p.invf    = (float*)alloc((size_t)NN*4);
    p.a_ws    = (float*)alloc((size_t)NN*2*4);
    p.ns      = (float*)alloc((size_t)NN*4);
    p.hlb     = (float*)alloc((size_t)NN*HC*4);
    p.hlf     = (float*)alloc((size_t)NN*HC*4);
    p.w       = (float*)alloc((size_t)2*NE*4);
    p.counts  = (int*)alloc((size_t)2*NN*4);
    p.starts  = (int*)alloc((size_t)2*(NN+1)*4);
    p.cursor  = (int*)alloc((size_t)2*NN*4);
    p.esrc    = (int*)alloc((size_t)2*NE*4);
    p.edst    = (int*)alloc((size_t)2*NE*4);
    p.out     = (float*)d_out;

    hipMemsetAsync(p.counts, 0, (size_t)2*NN*4, stream);
    k0_kernel<<<512 + NB, 256, 0, stream>>>(p);
    k1_kernel<<<PB_BODY + PB_FACE, 256, 0, stream>>>(p);
    k2_kernel<<<2 + NN/4 + NN/4 + NN/4, 256, 0, stream>>>(p);
    fill_kernel<<<(2*NE)/256, 256, 0, stream>>>(p);
    wdot_kernel<<<2*(NE/16), 256, 0, stream>>>(p);
    gather_kernel<<<NN/4, 256, 0, stream>>>(p);
}